// Round 1
// baseline (144.367 us; speedup 1.0000x reference)
//
#include <hip/hip_runtime.h>

// Varlen causal GQA prefill attention, B=4 S=2048 Hq=16 Hkv=4 D=128 (fp32 io).
// Strategy: pre-pass packs K and V^T into bf16 swizzled LDS-image tiles in d_ws;
// main kernel = flash attention, 128-row Q tile / block (4 waves x 32 rows),
// KVBLK=64, mfma_f32_16x16x32_bf16, staging via global_load_lds (16B).

typedef __attribute__((ext_vector_type(8))) short bs8;   // 8 bf16 (guide: short8 frag)
typedef __attribute__((ext_vector_type(4))) float f4;
typedef __attribute__((ext_vector_type(4))) unsigned short u16x4;
typedef unsigned short u16;
typedef unsigned int u32;

#define B_ 4
#define S_ 2048
#define HQ_ 16
#define HKV_ 4
#define D_ 128
#define QBLK 128
#define KVBLK 64
#define NQT (S_ / QBLK)      // 16
#define NKT_TOT (S_ / KVBLK) // 32
#define TILE_ELEMS 8192      // 64*128 (or 128*64) bf16 elems = 16KB

__device__ __forceinline__ u16 f2bf(float f) {  // fp32 -> bf16 RNE
  u32 u = __float_as_uint(f);
  u += 0x7fffu + ((u >> 16) & 1u);
  return (u16)(u >> 16);
}

// ---- pre-pass 1: K fp32 [T][512] -> bf16 swizzled K-tile images -------------
// image elem(kv,d) = kv*128 + (d ^ ((kv&7)<<3))   (byte-XOR ((kv&7)<<4))
__global__ void pack_k(const float* __restrict__ k, u16* __restrict__ kp) {
  int g = blockIdx.x * 256 + threadIdx.x;     // over T*512/4 float4s
  int row = g >> 7;
  int col = (g & 127) << 2;
  int h = col >> 7, d0 = col & 127;
  int b = row >> 11, s = row & 2047;
  int kt = s >> 6, kv = s & 63;
  float4 vv = *(const float4*)(k + (size_t)row * 512 + col);
  int ti = (b * HKV_ + h) * NKT_TOT + kt;
  int e = kv * 128 + (d0 ^ ((kv & 7) << 3));  // d0%4==0, XOR mult-of-8 -> contiguous 4
  u16x4 o;
  o.x = f2bf(vv.x); o.y = f2bf(vv.y); o.z = f2bf(vv.z); o.w = f2bf(vv.w);
  *(u16x4*)(kp + (size_t)ti * TILE_ELEMS + e) = o;
}

// ---- pre-pass 2: V fp32 [T][512] -> bf16 swizzled V^T-tile images -----------
// image elem(d,kvr) = d*64 + (kvr ^ ((d&7)<<3)); built in LDS, copied out linearly.
__global__ void pack_v(const float* __restrict__ v, u16* __restrict__ vp) {
  __shared__ u16 img[TILE_ELEMS];
  int ti = blockIdx.x;                 // (b*HKV+h)*32 + kt
  int kt = ti & 31;
  int bh = ti >> 5;
  int h = bh & 3, b = bh >> 2;
  int t = threadIdx.x;
#pragma unroll
  for (int p = 0; p < 8; ++p) {
    int t2 = p * 256 + t;              // 2048 float4s
    int kvr = t2 >> 5;
    int d0 = (t2 & 31) << 2;
    float4 vv = *(const float4*)(v + (size_t)(b * S_ + kt * 64 + kvr) * 512 + h * 128 + d0);
    float a[4] = {vv.x, vv.y, vv.z, vv.w};
#pragma unroll
    for (int j = 0; j < 4; ++j) {
      int d = d0 + j;
      img[d * 64 + (kvr ^ ((d & 7) << 3))] = f2bf(a[j]);
    }
  }
  __syncthreads();
#pragma unroll
  for (int p = 0; p < 4; ++p) {
    int e0 = (p * 256 + t) * 8;
    *(bs8*)(vp + (size_t)ti * TILE_ELEMS + e0) = *(const bs8*)&img[e0];
  }
}

// ---- main flash attention ---------------------------------------------------
__device__ __forceinline__ void gl2lds(const u16* g, u16* l) {
  __builtin_amdgcn_global_load_lds((const __attribute__((address_space(1))) void*)g,
                                   (__attribute__((address_space(3))) void*)l,
                                   16, 0, 0);
}

__global__ __launch_bounds__(256, 2) void attn_fwd(
    const float* __restrict__ q, const u16* __restrict__ kp,
    const u16* __restrict__ vp, float* __restrict__ out) {
  __shared__ u16 Ks[TILE_ELEMS];       // swizzled [64 kv][128 d]
  __shared__ u16 Vs[TILE_ELEMS];       // swizzled V^T [128 d][64 kv]
  __shared__ u16 Ps[4][32 * 64];       // per-wave swizzled P [32 q][64 kv]

  const int bx = blockIdx.x;
  const int qt = (NQT - 1) - (bx >> 6);   // heavy tiles first
  const int bh = bx & 63;
  const int b = bh >> 4, hq = bh & 15, hkv = hq >> 2;
  const int w = threadIdx.x >> 6, lane = threadIdx.x & 63;
  const int l16 = lane & 15, lhi = lane >> 4;
  const int q0 = qt * QBLK;
  const float scale = 0.08838834764831845f;  // 1/sqrt(128)

  // Q fragments in registers (scale folded in). A-frag: row=l&15, k=(l>>4)*8+i.
  bs8 qf[2][4];
#pragma unroll
  for (int rs = 0; rs < 2; ++rs) {
    int row = b * S_ + q0 + w * 32 + rs * 16 + l16;
    const float* qrow = q + (size_t)row * 2048 + hq * 128;
#pragma unroll
    for (int ks = 0; ks < 4; ++ks) {
      const float* p0 = qrow + ks * 32 + lhi * 8;
      float4 a = *(const float4*)p0;
      float4 c = *(const float4*)(p0 + 4);
      bs8 f;
      f[0] = (short)f2bf(a.x * scale); f[1] = (short)f2bf(a.y * scale);
      f[2] = (short)f2bf(a.z * scale); f[3] = (short)f2bf(a.w * scale);
      f[4] = (short)f2bf(c.x * scale); f[5] = (short)f2bf(c.y * scale);
      f[6] = (short)f2bf(c.z * scale); f[7] = (short)f2bf(c.w * scale);
      qf[rs][ks] = f;
    }
  }

  f4 O[2][8];
  float m_r[2][4], l_r[2][4];
#pragma unroll
  for (int rs = 0; rs < 2; ++rs) {
#pragma unroll
    for (int r = 0; r < 4; ++r) { m_r[rs][r] = -1e30f; l_r[rs][r] = 0.f; }
#pragma unroll
    for (int dt = 0; dt < 8; ++dt) O[rs][dt] = f4{0.f, 0.f, 0.f, 0.f};
  }

  const int nkt = 2 * qt + 2;
  const size_t tbase = (size_t)((b * HKV_ + hkv) * NKT_TOT) * TILE_ELEMS;
  const u16* kbase = kp + tbase;
  const u16* vbase = vp + tbase;
  const int myrowmax = q0 + w * 32 + 31;

  for (int kt = 0; kt < nkt; ++kt) {
    __syncthreads();  // prev tile fully consumed before overwrite
    {
      const u16* kg = kbase + (size_t)kt * TILE_ELEMS;
      const u16* vg = vbase + (size_t)kt * TILE_ELEMS;
#pragma unroll
      for (int j = 0; j < 4; ++j) {
        int chunk = w * 4 + j;              // wave-uniform LDS dst
        int eoff = chunk * 512 + lane * 8;  // per-lane global src
        gl2lds(kg + eoff, &Ks[chunk * 512]);
        gl2lds(vg + eoff, &Vs[chunk * 512]);
      }
    }
    asm volatile("s_waitcnt vmcnt(0)" ::: "memory");
    __syncthreads();

    if (kt * KVBLK <= myrowmax) {  // wave-level causal tile skip
      // ---- QK^T: S[16x64] per rowset -----------------------------------
      f4 Sf[2][4];
#pragma unroll
      for (int rs = 0; rs < 2; ++rs)
#pragma unroll
        for (int n = 0; n < 4; ++n) Sf[rs][n] = f4{0.f, 0.f, 0.f, 0.f};
#pragma unroll
      for (int ks = 0; ks < 4; ++ks) {
#pragma unroll
        for (int n = 0; n < 4; ++n) {
          int kv = n * 16 + l16;
          bs8 kf = *(const bs8*)&Ks[kv * 128 + ((ks * 32 + lhi * 8) ^ ((kv & 7) << 3))];
          Sf[0][n] = __builtin_amdgcn_mfma_f32_16x16x32_bf16(qf[0][ks], kf, Sf[0][n], 0, 0, 0);
          Sf[1][n] = __builtin_amdgcn_mfma_f32_16x16x32_bf16(qf[1][ks], kf, Sf[1][n], 0, 0, 0);
        }
      }
      // ---- causal mask (only last two tiles can straddle the diagonal) --
      if (kt >= 2 * qt) {
#pragma unroll
        for (int rs = 0; rs < 2; ++rs) {
          int qpos = q0 + w * 32 + rs * 16 + lhi * 4;
#pragma unroll
          for (int n = 0; n < 4; ++n) {
            int kpos = kt * KVBLK + n * 16 + l16;
#pragma unroll
            for (int r = 0; r < 4; ++r)
              if (kpos > qpos + r) Sf[rs][n][r] = -1e30f;
          }
        }
      }
      // ---- online softmax (C layout: col=l&15, row=(l>>4)*4+r) ----------
#pragma unroll
      for (int rs = 0; rs < 2; ++rs) {
        float mx[4];
#pragma unroll
        for (int r = 0; r < 4; ++r)
          mx[r] = fmaxf(fmaxf(Sf[rs][0][r], Sf[rs][1][r]),
                        fmaxf(Sf[rs][2][r], Sf[rs][3][r]));
#pragma unroll
        for (int r = 0; r < 4; ++r) {
          mx[r] = fmaxf(mx[r], __shfl_xor(mx[r], 1, 64));
          mx[r] = fmaxf(mx[r], __shfl_xor(mx[r], 2, 64));
          mx[r] = fmaxf(mx[r], __shfl_xor(mx[r], 4, 64));
          mx[r] = fmaxf(mx[r], __shfl_xor(mx[r], 8, 64));
        }
#pragma unroll
        for (int r = 0; r < 4; ++r) {
          float mn = fmaxf(m_r[rs][r], mx[r]);
          float alpha = __expf(m_r[rs][r] - mn);
          m_r[rs][r] = mn;
          float psum = 0.f;
#pragma unroll
          for (int n = 0; n < 4; ++n) {
            float pe = __expf(Sf[rs][n][r] - mn);
            Sf[rs][n][r] = pe;   // reuse Sf as P
            psum += pe;
          }
          l_r[rs][r] = l_r[rs][r] * alpha + psum;  // per-lane partial; reduced at end
#pragma unroll
          for (int dt = 0; dt < 8; ++dt) O[rs][dt][r] *= alpha;
        }
        // write P to per-wave swizzled LDS
        int rp0 = rs * 16 + lhi * 4;
#pragma unroll
        for (int r = 0; r < 4; ++r) {
          int rp = rp0 + r;
#pragma unroll
          for (int n = 0; n < 4; ++n) {
            int col = n * 16 + l16;
            Ps[w][rp * 64 + (col ^ ((rp & 7) << 3))] = f2bf(Sf[rs][n][r]);
          }
        }
      }
      asm volatile("s_waitcnt lgkmcnt(0)" ::: "memory");  // cross-lane P visibility
      // ---- PV: O += P[16x64] * V[64x128] --------------------------------
#pragma unroll
      for (int ks2 = 0; ks2 < 2; ++ks2) {
        bs8 pa[2];
#pragma unroll
        for (int rs = 0; rs < 2; ++rs) {
          int rp = rs * 16 + l16;
          pa[rs] = *(const bs8*)&Ps[w][rp * 64 + ((ks2 * 32 + lhi * 8) ^ ((rp & 7) << 3))];
        }
#pragma unroll
        for (int dt = 0; dt < 8; ++dt) {
          int d = dt * 16 + l16;
          bs8 vb = *(const bs8*)&Vs[d * 64 + ((ks2 * 32 + lhi * 8) ^ ((d & 7) << 3))];
          O[0][dt] = __builtin_amdgcn_mfma_f32_16x16x32_bf16(pa[0], vb, O[0][dt], 0, 0, 0);
          O[1][dt] = __builtin_amdgcn_mfma_f32_16x16x32_bf16(pa[1], vb, O[1][dt], 0, 0, 0);
        }
      }
    }
  }

  // ---- epilogue: reduce l across the 16-lane row group, normalize, store ----
#pragma unroll
  for (int rs = 0; rs < 2; ++rs) {
#pragma unroll
    for (int r = 0; r < 4; ++r) {
      float ls = l_r[rs][r];
      ls += __shfl_xor(ls, 1, 64);
      ls += __shfl_xor(ls, 2, 64);
      ls += __shfl_xor(ls, 4, 64);
      ls += __shfl_xor(ls, 8, 64);
      float inv = 1.f / ls;
      int row = b * S_ + q0 + w * 32 + rs * 16 + lhi * 4 + r;
      float* orow = out + (size_t)row * 2048 + hq * 128 + l16;
#pragma unroll
      for (int dt = 0; dt < 8; ++dt) orow[dt * 16] = O[rs][dt][r] * inv;
    }
  }
}

extern "C" void kernel_launch(void* const* d_in, const int* in_sizes, int n_in,
                              void* d_out, int out_size, void* d_ws, size_t ws_size,
                              hipStream_t stream) {
  const float* q = (const float*)d_in[0];
  const float* k = (const float*)d_in[1];
  const float* v = (const float*)d_in[2];
  float* out = (float*)d_out;
  u16* kp = (u16*)d_ws;                               // 8 MB: packed K tiles
  u16* vp = kp + (size_t)B_ * HKV_ * NKT_TOT * TILE_ELEMS;  // 8 MB: packed V^T tiles

  pack_k<<<(B_ * S_ * 512 / 4) / 256, 256, 0, stream>>>(k, kp);
  pack_v<<<B_ * HKV_ * NKT_TOT, 256, 0, stream>>>(v, vp);
  attn_fwd<<<B_ * HQ_ * NQT, 256, 0, stream>>>(q, kp, vp, out);
}

// Round 2
// 107.902 us; speedup vs baseline: 1.3379x; 1.3379x over previous
//
#include <hip/hip_runtime.h>

// Varlen causal GQA prefill attention, B=4 S=2048 Hq=16 Hkv=4 D=128 (fp32 io).
// R2: 32x32x16 MFMA, swapped QK^T (S[kv][q]), in-register P via
// cvt_pk_bf16 + permlane32_swap (T12), defer-max (T13), double-buffered
// K/V prefetch (T3-lite), per-phase conflict-free swizzled K/V images.

typedef __attribute__((ext_vector_type(8))) short bs8;       // 8 bf16 (4 VGPR)
typedef __attribute__((ext_vector_type(16))) float f16x;     // 32x32 acc
typedef __attribute__((ext_vector_type(4))) unsigned int u32x4;
typedef __attribute__((ext_vector_type(4))) unsigned short u16x4;
typedef unsigned short u16;
typedef unsigned int u32;

#define B_ 4
#define S_ 2048
#define HQ_ 16
#define HKV_ 4
#define NQT 16        // q-tiles of 128
#define NKT_TOT 32    // kv-tiles of 64
#define TILE_ELEMS 8192  // 64x128 bf16 = 16KB

__device__ __forceinline__ u16 f2bf(float f) {  // fp32 -> bf16 RNE
  u32 u = __float_as_uint(f);
  u += 0x7fffu + ((u >> 16) & 1u);
  return (u16)(u >> 16);
}

// ---- pre-pass 1: K -> bf16 tile images, elem(kv,d) = kv*128 + (d ^ 8*(kv&15))
__global__ void pack_k(const float* __restrict__ k, u16* __restrict__ kp) {
  int g = blockIdx.x * 256 + threadIdx.x;
  int row = g >> 7;
  int col = (g & 127) << 2;
  int h = col >> 7, d0 = col & 127;
  int b = row >> 11, s = row & 2047;
  int kt = s >> 6, kv = s & 63;
  float4 vv = *(const float4*)(k + (size_t)row * 512 + col);
  int ti = (b * HKV_ + h) * NKT_TOT + kt;
  int e = kv * 128 + (d0 ^ (8 * (kv & 15)));  // d0%4==0; XOR touches bits>=3
  u16x4 o;
  o.x = f2bf(vv.x); o.y = f2bf(vv.y); o.z = f2bf(vv.z); o.w = f2bf(vv.w);
  *(u16x4*)(kp + (size_t)ti * TILE_ELEMS + e) = o;
}

// ---- pre-pass 2: V -> bf16 V^T images, elem(d,kv) =
//        (d>>1)*128 + (d&1)*64 + (kv ^ 8*((d>>1)&7)); built in LDS, copied linear.
__global__ void pack_v(const float* __restrict__ v, u16* __restrict__ vp) {
  __shared__ u16 img[TILE_ELEMS];
  int ti = blockIdx.x;                 // (b*HKV+h)*32 + kt
  int kt = ti & 31;
  int bh = ti >> 5;
  int h = bh & 3, b = bh >> 2;
  int t = threadIdx.x;
#pragma unroll
  for (int p = 0; p < 8; ++p) {
    int t2 = p * 256 + t;
    int kvr = t2 >> 5;
    int d0 = (t2 & 31) << 2;
    float4 vv = *(const float4*)(v + (size_t)(b * S_ + kt * 64 + kvr) * 512 + h * 128 + d0);
    float a[4] = {vv.x, vv.y, vv.z, vv.w};
#pragma unroll
    for (int j = 0; j < 4; ++j) {
      int d = d0 + j;
      img[(d >> 1) * 128 + (d & 1) * 64 + (kvr ^ (8 * ((d >> 1) & 7)))] = f2bf(a[j]);
    }
  }
  __syncthreads();
#pragma unroll
  for (int p = 0; p < 4; ++p) {
    int e0 = (p * 256 + t) * 8;
    *(bs8*)(vp + (size_t)ti * TILE_ELEMS + e0) = *(const bs8*)&img[e0];
  }
}

// ---- main flash attention ---------------------------------------------------
__device__ __forceinline__ void gl2lds(const u16* g, u16* l) {
  __builtin_amdgcn_global_load_lds((const __attribute__((address_space(1))) void*)g,
                                   (__attribute__((address_space(3))) void*)l,
                                   16, 0, 0);
}

__global__ __launch_bounds__(256, 2) void attn_fwd(
    const float* __restrict__ q, const u16* __restrict__ kp,
    const u16* __restrict__ vp, float* __restrict__ out) {
  __shared__ u16 Ks[2][TILE_ELEMS];
  __shared__ u16 Vs[2][TILE_ELEMS];

  const int bx = blockIdx.x;
  const int qt = (NQT - 1) - (bx >> 6);   // heavy q-tiles first
  const int bh = bx & 63;
  const int b = bh >> 4, hq = bh & 15, hkv = hq >> 2;
  const int w = threadIdx.x >> 6, lane = threadIdx.x & 63;
  const int l31 = lane & 31, hi = lane >> 5;
  const int q0 = qt * 128;
  const float scale = 0.08838834764831845f;  // 1/sqrt(128)

  // Q B-frags in registers: qf[ki] = Q[q=l31][ki*16 + hi*8 + 0..7] * scale
  bs8 qf[8];
  {
    int row = b * S_ + q0 + w * 32 + l31;
    const float* qrow = q + (size_t)row * 2048 + hq * 128;
#pragma unroll
    for (int ki = 0; ki < 8; ++ki) {
      const float* p0 = qrow + ki * 16 + hi * 8;
      float4 a = *(const float4*)p0;
      float4 c = *(const float4*)(p0 + 4);
      bs8 f;
      f[0] = (short)f2bf(a.x * scale); f[1] = (short)f2bf(a.y * scale);
      f[2] = (short)f2bf(a.z * scale); f[3] = (short)f2bf(a.w * scale);
      f[4] = (short)f2bf(c.x * scale); f[5] = (short)f2bf(c.y * scale);
      f[6] = (short)f2bf(c.z * scale); f[7] = (short)f2bf(c.w * scale);
      qf[ki] = f;
    }
  }

  f16x O[4];
#pragma unroll
  for (int dt = 0; dt < 4; ++dt)
#pragma unroll
    for (int e = 0; e < 16; ++e) O[dt][e] = 0.f;
  float m_run = -1e30f, l_run = 0.f;

  const size_t tbase = (size_t)((b * HKV_ + hkv) * NKT_TOT) * TILE_ELEMS;
  const u16* kbase = kp + tbase;
  const u16* vbase = vp + tbase;
  const int nkt = 2 * qt + 2;
  const int myrowmax = q0 + w * 32 + 31;
  const int qpos = q0 + w * 32 + l31;

  const int swzk = 8 * (l31 & 15);               // K image read swizzle
  const int swzv = 8 * ((l31 >> 1) & 7);         // V image read swizzle
  const int vrowbase = (l31 >> 1) * 128 + (l31 & 1) * 64;

  // prologue: stage tile 0
#pragma unroll
  for (int j = 0; j < 4; ++j) {
    int c = w * 4 + j;
    gl2lds(kbase + c * 512 + lane * 8, &Ks[0][c * 512]);
    gl2lds(vbase + c * 512 + lane * 8, &Vs[0][c * 512]);
  }
  asm volatile("s_waitcnt vmcnt(0)" ::: "memory");
  __syncthreads();

  int cur = 0;
  for (int kt = 0; kt < nkt; ++kt) {
    // prefetch next tile into the other buffer (overlaps with compute below)
    if (kt + 1 < nkt) {
      const u16* kg = kbase + (size_t)(kt + 1) * TILE_ELEMS;
      const u16* vg = vbase + (size_t)(kt + 1) * TILE_ELEMS;
#pragma unroll
      for (int j = 0; j < 4; ++j) {
        int c = w * 4 + j;
        gl2lds(kg + c * 512 + lane * 8, &Ks[cur ^ 1][c * 512]);
        gl2lds(vg + c * 512 + lane * 8, &Vs[cur ^ 1][c * 512]);
      }
    }

    if (kt * 64 <= myrowmax) {  // wave-level causal tile skip (no barriers inside)
      // ---- QK^T swapped: S[kv][q], col=lane&31=q ----
      f16x Sa[2];
#pragma unroll
      for (int kb = 0; kb < 2; ++kb)
#pragma unroll
        for (int e = 0; e < 16; ++e) Sa[kb][e] = 0.f;

      __builtin_amdgcn_s_setprio(1);
#pragma unroll
      for (int ki = 0; ki < 8; ++ki) {
        int koff = (ki * 16 + hi * 8) ^ swzk;
#pragma unroll
        for (int kb = 0; kb < 2; ++kb) {
          bs8 kf = *(const bs8*)&Ks[cur][(kb * 32 + l31) * 128 + koff];
          Sa[kb] = __builtin_amdgcn_mfma_f32_32x32x16_bf16(kf, qf[ki], Sa[kb], 0, 0, 0);
        }
      }
      __builtin_amdgcn_s_setprio(0);

      // ---- causal mask (only the last two tiles straddle the diagonal) ----
      if (kt >= 2 * qt) {
#pragma unroll
        for (int kb = 0; kb < 2; ++kb)
#pragma unroll
          for (int r = 0; r < 16; ++r) {
            int kvpos = kt * 64 + kb * 32 + (r & 3) + 8 * (r >> 2) + 4 * hi;
            if (kvpos > qpos) Sa[kb][r] = -1e30f;
          }
      }

      // ---- online softmax: lane owns column q=lane&31 (half the kv rows) ----
      float pmax = Sa[0][0];
#pragma unroll
      for (int kb = 0; kb < 2; ++kb)
#pragma unroll
        for (int r = 0; r < 16; ++r) pmax = fmaxf(pmax, Sa[kb][r]);
      pmax = fmaxf(pmax, __shfl_xor(pmax, 32, 64));

      if (__any(pmax > m_run + 8.0f)) {  // defer-max: rescale only when needed
        float mnew = fmaxf(m_run, pmax);
        float alpha = __expf(m_run - mnew);
        m_run = mnew;
        l_run *= alpha;
#pragma unroll
        for (int r = 0; r < 16; ++r) {
          float ar = __shfl(alpha, (r & 3) + 8 * (r >> 2) + 4 * hi, 64);
#pragma unroll
          for (int dt = 0; dt < 4; ++dt) O[dt][r] *= ar;
        }
      }

      float psum = 0.f;
#pragma unroll
      for (int kb = 0; kb < 2; ++kb)
#pragma unroll
        for (int r = 0; r < 16; ++r) {
          float p = __expf(Sa[kb][r] - m_run);
          Sa[kb][r] = p;
          psum += p;
        }
      l_run += psum;

      // ---- P f32 -> bf16 A-frags: cvt_pk pairs + permlane32_swap (T12) ----
      bs8 pf[2][2];
#pragma unroll
      for (int kb = 0; kb < 2; ++kb) {
        u32 pk_[8];
#pragma unroll
        for (int j = 0; j < 8; ++j) {
          float lo = Sa[kb][2 * j], hif = Sa[kb][2 * j + 1];
          asm("v_cvt_pk_bf16_f32 %0, %1, %2" : "=v"(pk_[j]) : "v"(lo), "v"(hif));
        }
#pragma unroll
        for (int ks = 0; ks < 2; ++ks) {
          auto s0 = __builtin_amdgcn_permlane32_swap((int)pk_[4 * ks], (int)pk_[4 * ks + 2], false, false);
          auto s1 = __builtin_amdgcn_permlane32_swap((int)pk_[4 * ks + 1], (int)pk_[4 * ks + 3], false, false);
          u32x4 fw;
          fw[0] = (u32)s0[0]; fw[1] = (u32)s1[0]; fw[2] = (u32)s0[1]; fw[3] = (u32)s1[1];
          pf[kb][ks] = __builtin_bit_cast(bs8, fw);
        }
      }

      // ---- PV: O[q][d] += P[q][kv] * V[kv][d], col=lane&31=d ----
      __builtin_amdgcn_s_setprio(1);
#pragma unroll
      for (int dt = 0; dt < 4; ++dt) {
#pragma unroll
        for (int kb = 0; kb < 2; ++kb)
#pragma unroll
          for (int ks = 0; ks < 2; ++ks) {
            int kvoff = (kb * 32 + ks * 16 + hi * 8) ^ swzv;
            bs8 vb = *(const bs8*)&Vs[cur][dt * 2048 + vrowbase + kvoff];
            O[dt] = __builtin_amdgcn_mfma_f32_32x32x16_bf16(pf[kb][ks], vb, O[dt], 0, 0, 0);
          }
      }
      __builtin_amdgcn_s_setprio(0);
    }

    asm volatile("s_waitcnt vmcnt(0)" ::: "memory");
    __syncthreads();
    cur ^= 1;
  }

  // ---- epilogue: combine l halves, normalize, coalesced store ----
  float lt = l_run + __shfl_xor(l_run, 32, 64);
  float inv = 1.0f / lt;
  const int orow0 = b * S_ + q0 + w * 32;
#pragma unroll
  for (int r = 0; r < 16; ++r) {
    int qr = (r & 3) + 8 * (r >> 2) + 4 * hi;
    float li = __shfl(inv, qr, 64);
    float* op = out + (size_t)(orow0 + qr) * 2048 + hq * 128 + l31;
#pragma unroll
    for (int dt = 0; dt < 4; ++dt) op[dt * 32] = O[dt][r] * li;
  }
}

extern "C" void kernel_launch(void* const* d_in, const int* in_sizes, int n_in,
                              void* d_out, int out_size, void* d_ws, size_t ws_size,
                              hipStream_t stream) {
  const float* q = (const float*)d_in[0];
  const float* k = (const float*)d_in[1];
  const float* v = (const float*)d_in[2];
  float* out = (float*)d_out;
  u16* kp = (u16*)d_ws;                                       // 8 MB K images
  u16* vp = kp + (size_t)B_ * HKV_ * NKT_TOT * TILE_ELEMS;    // 8 MB V^T images

  pack_k<<<(B_ * S_ * 512 / 4) / 256, 256, 0, stream>>>(k, kp);
  pack_v<<<B_ * HKV_ * NKT_TOT, 256, 0, stream>>>(v, vp);
  attn_fwd<<<B_ * HQ_ * NQT, 256, 0, stream>>>(q, kp, vp, out);
}